// Round 1
// baseline (1042.728 us; speedup 1.0000x reference)
//
#include <hip/hip_runtime.h>

#define D 64
#define BETA 0.9f
#define ALPHA 0.1f

// One wave (64 lanes) per edge; lane = feature index d.
// xbuf == nullptr -> layer 0: gather from concat(user_emb, item_emb).
__global__ void spmm_edges(const int* __restrict__ rows, const int* __restrict__ cols,
                           const float* __restrict__ vals,
                           const float* __restrict__ uemb, const float* __restrict__ iemb,
                           const float* __restrict__ xbuf,
                           int U, int E, float* __restrict__ y) {
    int lane = threadIdx.x & (D - 1);
    long long wid = (((long long)blockIdx.x * blockDim.x) + threadIdx.x) >> 6;
    long long wstride = ((long long)gridDim.x * blockDim.x) >> 6;
    for (long long e = wid; e < E; e += wstride) {
        int r = rows[e];
        int c = cols[e];
        float v = vals[e];
        float xv;
        if (xbuf) {
            xv = xbuf[(long long)c * D + lane];
        } else {
            xv = (c < U) ? uemb[(long long)c * D + lane]
                         : iemb[(long long)(c - U) * D + lane];
        }
        unsafeAtomicAdd(&y[(long long)r * D + lane], v * xv);
    }
}

// Layer-3 SpMM restricted to flagged output rows (~4% of edges do work).
__global__ void spmm_edges_masked(const int* __restrict__ rows, const int* __restrict__ cols,
                                  const float* __restrict__ vals,
                                  const int* __restrict__ flag,
                                  const float* __restrict__ xbuf,
                                  int E, float* __restrict__ y) {
    int lane = threadIdx.x & (D - 1);
    long long wid = (((long long)blockIdx.x * blockDim.x) + threadIdx.x) >> 6;
    long long wstride = ((long long)gridDim.x * blockDim.x) >> 6;
    for (long long e = wid; e < E; e += wstride) {
        int r = rows[e];
        if (flag[r] == 0) continue;
        int c = cols[e];
        float v = vals[e];
        float xv = xbuf[(long long)c * D + lane];
        unsafeAtomicAdd(&y[(long long)r * D + lane], v * xv);
    }
}

// y = y*BETA + x0*ALPHA  (element-wise, float4-vectorized)
__global__ void combine_kernel(float* __restrict__ y, const float* __restrict__ x0,
                               long long n4) {
    long long i = (long long)blockIdx.x * blockDim.x + threadIdx.x;
    long long stride = (long long)gridDim.x * blockDim.x;
    for (; i < n4; i += stride) {
        float4 a = ((const float4*)y)[i];
        float4 b = ((const float4*)x0)[i];
        a.x = a.x * BETA + b.x * ALPHA;
        a.y = a.y * BETA + b.y * ALPHA;
        a.z = a.z * BETA + b.z * ALPHA;
        a.w = a.w * BETA + b.w * ALPHA;
        ((float4*)y)[i] = a;
    }
}

// sel[s*64+d] = x0[row(s)*64+d] for the 2B needed rows
__global__ void gather_sel(const int* __restrict__ users, const int* __restrict__ items,
                           int B, int U, const float* __restrict__ x0,
                           float* __restrict__ sel) {
    int t = blockIdx.x * blockDim.x + threadIdx.x;
    if (t >= 2 * B * D) return;
    int s = t >> 6;
    int d = t & (D - 1);
    int r = (s < B) ? users[s] : U + items[s - B];
    sel[t] = x0[(long long)r * D + d];
}

__global__ void set_flags(const int* __restrict__ users, const int* __restrict__ items,
                          int B, int U, int* __restrict__ flag) {
    int s = blockIdx.x * blockDim.x + threadIdx.x;
    if (s < B) {
        flag[users[s]] = 1;
    } else if (s < 2 * B) {
        flag[U + items[s - B]] = 1;
    }
}

// out[s*64+d] = (ego2[row(s)*64+d]*BETA + sel[s*64+d]*ALPHA) / gamma
__global__ void finalize(const int* __restrict__ users, const int* __restrict__ items,
                         int B, int U, const float* __restrict__ ego2,
                         const float* __restrict__ sel, float inv_gamma,
                         float* __restrict__ out) {
    int t = blockIdx.x * blockDim.x + threadIdx.x;
    if (t >= 2 * B * D) return;
    int s = t >> 6;
    int d = t & (D - 1);
    int r = (s < B) ? users[s] : U + items[s - B];
    out[t] = (ego2[(long long)r * D + d] * BETA + sel[t] * ALPHA) * inv_gamma;
}

extern "C" void kernel_launch(void* const* d_in, const int* in_sizes, int n_in,
                              void* d_out, int out_size, void* d_ws, size_t ws_size,
                              hipStream_t stream) {
    const int*   users = (const int*)d_in[0];
    const int*   items = (const int*)d_in[1];
    const float* uemb  = (const float*)d_in[2];
    const float* iemb  = (const float*)d_in[3];
    const int*   arows = (const int*)d_in[4];
    const int*   acols = (const int*)d_in[5];
    const float* avals = (const float*)d_in[6];

    const int B = in_sizes[0];
    const int U = in_sizes[2] / D;
    const int I = in_sizes[3] / D;
    const int N = U + I;
    const int E = in_sizes[4];

    // gamma = beta^3 + alpha*(1 + beta + beta^2) == 1.0 exactly for (0.9, 0.1)
    const double gamma_d = (double)BETA * BETA * BETA +
                           (double)ALPHA * (1.0 + (double)BETA + (double)BETA * BETA);
    const float inv_gamma = (float)(1.0 / gamma_d);

    // Workspace layout
    char* ws = (char*)d_ws;
    const size_t nd_bytes = (size_t)N * D * sizeof(float);
    auto align256 = [](size_t x) { return (x + 255) & ~(size_t)255; };
    float* x0   = (float*)ws; ws += align256(nd_bytes);   // layer-0 result, later reused as layer-3 accumulator
    float* ego1 = (float*)ws; ws += align256(nd_bytes);   // layer-1+2 combined state
    float* sel  = (float*)ws; ws += align256((size_t)2 * B * D * sizeof(float));
    int*   flag = (int*)ws;   ws += align256((size_t)N * sizeof(int));

    const int threads = 256;
    const int spmm_blocks = 4096;
    const int tot = 2 * B * D;

    // Layer 0: x0 = A @ concat(uemb, iemb)
    hipMemsetAsync(x0, 0, nd_bytes, stream);
    spmm_edges<<<spmm_blocks, threads, 0, stream>>>(arows, acols, avals, uemb, iemb,
                                                    nullptr, U, E, x0);
    // Save x0 at the needed rows (x0's buffer gets recycled later)
    gather_sel<<<(tot + threads - 1) / threads, threads, 0, stream>>>(users, items, B, U,
                                                                      x0, sel);

    // Layer 1: ego1 = (A @ x0)*beta + x0*alpha
    hipMemsetAsync(ego1, 0, nd_bytes, stream);
    spmm_edges<<<spmm_blocks, threads, 0, stream>>>(arows, acols, avals, nullptr, nullptr,
                                                    x0, U, E, ego1);
    combine_kernel<<<2048, threads, 0, stream>>>(ego1, x0, (long long)N * D / 4);

    // Layer 2, only for needed rows: ego2[r] = A[r,:] @ ego1   (r flagged)
    hipMemsetAsync(flag, 0, (size_t)N * sizeof(int), stream);
    set_flags<<<(2 * B + threads - 1) / threads, threads, 0, stream>>>(users, items, B, U,
                                                                       flag);
    hipMemsetAsync(x0, 0, nd_bytes, stream);  // reuse x0 buffer as ego2 accumulator
    spmm_edges_masked<<<spmm_blocks, threads, 0, stream>>>(arows, acols, avals, flag,
                                                           ego1, E, x0);

    // out = (ego2*beta + x0_sel*alpha) / gamma
    finalize<<<(tot + threads - 1) / threads, threads, 0, stream>>>(users, items, B, U,
                                                                    x0, sel, inv_gamma,
                                                                    (float*)d_out);
}